// Round 8
// baseline (76.289 us; speedup 1.0000x reference)
//
#include <hip/hip_runtime.h>

#define NB  16
#define NTQ 64
#define NTV 256
#define ND  512
#define NU  512

typedef _Float16 half8_t __attribute__((ext_vector_type(8)));
typedef _Float16 half4_t __attribute__((ext_vector_type(4)));
typedef _Float16 half2_t __attribute__((ext_vector_type(2)));
typedef float floatx4 __attribute__((ext_vector_type(4)));

#if __has_builtin(__builtin_amdgcn_fdot2)
#define FDOT2(a, b, c) __builtin_amdgcn_fdot2((a), (b), (c), false)
#else
#define FDOT2(a, b, c) ((c) + (float)((a)[0]) * (float)((b)[0]) + (float)((a)[1]) * (float)((b)[1]))
#endif
#if __has_builtin(__builtin_amdgcn_rcph)
#define RCPH(x) ((_Float16)__builtin_amdgcn_rcph((_Float16)(x)))
#else
#define RCPH(x) ((_Float16)__builtin_amdgcn_rcpf((float)(x)))
#endif

__device__ __forceinline__ float wred_sum(float x) {
#pragma unroll
    for (int m = 1; m < 64; m <<= 1) x += __shfl_xor(x, m, 64);
    return x;
}
__device__ __forceinline__ float wred_max(float x) {
#pragma unroll
    for (int m = 1; m < 64; m <<= 1) x = fmaxf(x, __shfl_xor(x, m, 64));
    return x;
}

// ---------------- K1: prep (transpose W1/W2 -> f16; Vwh; CVb). Converts fused into K2.
__global__ __launch_bounds__(256) void prep_kernel(
        const float* __restrict__ W1, const float* __restrict__ W2,
        const float* __restrict__ Vw, const float* __restrict__ Vb,
        _Float16* __restrict__ W1T, _Float16* __restrict__ W2T,
        _Float16* __restrict__ Vwh, float* __restrict__ CVb) {
    const int blk = blockIdx.x;
    const int t = threadIdx.x;
    __shared__ float tb[32][33];
    if (blk < 512) {
        const float* W = (blk < 256) ? W1 : W2;
        _Float16* WT = (blk < 256) ? W1T : W2T;
        const int tile = blk & 255;
        const int tr = tile >> 4, tc = tile & 15;
        const int c = t & 31, r8 = t >> 5;
#pragma unroll
        for (int i = 0; i < 4; ++i) {
            int r = r8 + 8 * i;
            tb[r][c] = W[(tr * 32 + r) * 512 + tc * 32 + c];
        }
        __syncthreads();
#pragma unroll
        for (int i = 0; i < 4; ++i) {
            int r = r8 + 8 * i;
            WT[(tc * 32 + r) * 512 + tr * 32 + c] = (_Float16)tb[c][r];
        }
    } else {
        const float v0 = Vw[t], v1 = Vw[t + 256];
        Vwh[t] = (_Float16)v0;
        Vwh[t + 256] = (_Float16)v1;
        float s = wred_sum(v0 + v1);
        const int l = t & 63, w = t >> 6;
        __shared__ float ws4[4];
        if (l == 0) ws4[w] = s;
        __syncthreads();
        if (t == 0) CVb[0] = ws4[0] + ws4[1] + ws4[2] + ws4[3] + Vb[0];
    }
}

// ---------------- K2: fused convert + projections (f16 MFMA) + exp2 epilogue.
// A-side staged DIRECTLY from f32 (query / values) with on-the-fly f16 convert;
// v-side tn==0 blocks also emit vh (f16 values) for the ctx kernel.
// bid < 32 : Eqh[m=(b,q)][u] = f16(min(exp2(KC*(query@W1 + b1)), 60000))
// bid >= 32: Evp[b][v][u]    = f16(min(exp2(KC*(values@W2 + b2)), 60000))  (v-major)
__global__ __launch_bounds__(256) void proj_gemm_kernel(
        const float* __restrict__ query, const float* __restrict__ values,
        const _Float16* __restrict__ W1T, const _Float16* __restrict__ W2T,
        const float* __restrict__ b1, const float* __restrict__ b2,
        _Float16* __restrict__ Eqh, _Float16* __restrict__ Evp,
        _Float16* __restrict__ vh) {
    __shared__ __align__(16) _Float16 As[128 * 40];
    __shared__ __align__(16) _Float16 Bs[128 * 40];
    const float KC = 2.8853900817779268f;  // 2*log2(e)
    const int bid = blockIdx.x;
    const int t = threadIdx.x;
    const int l = t & 63, w = t >> 6;

    const float* Agf; const _Float16* Bg;
    const float* bias; _Float16* Cg;
    int tm, tn; bool writeVh = false; _Float16* vhout = nullptr;
    if (bid < 32) {
        tm = (bid >> 2) * 128; tn = (bid & 3) * 128;
        Agf = query; Bg = W1T; bias = b1; Cg = Eqh;
    } else {
        const int v = bid - 32;
        const int bb = v >> 3, r = v & 7;
        tm = (r & 1) * 128; tn = (r >> 1) * 128;
        Agf = values + bb * (NTV * ND); Bg = W2T; bias = b2;
        Cg = Evp + bb * (NTV * NU);
        writeVh = (tn == 0);
        vhout = vh + bb * (NTV * ND);
    }

    floatx4 acc[4][4] = {};

    // A staging map: row0 = t>>3 (+32*s), col4 = (t&7)*4  -> 8 lanes cover a 128B row seg
    const int ar = t >> 3, ac = (t & 7) * 4;
    // B staging map (f16 source): srow = t>>1, spart = (t&1)*16
    const int srow = t >> 1, spart = (t & 1) * 16;
    const int wm = (w >> 1) * 64, wn = (w & 1) * 64;
    const int lr = l & 15, lk = l >> 4;

    for (int kk = 0; kk < 512; kk += 32) {
        __syncthreads();
        // ---- A-side: f32 -> f16 convert staging (4 x 32 rows)
#pragma unroll
        for (int s = 0; s < 4; ++s) {
            const float4 f = *(const float4*)(Agf + (tm + ar + s * 32) * 512 + kk + ac);
            half4_t h4 = {(_Float16)f.x, (_Float16)f.y, (_Float16)f.z, (_Float16)f.w};
            *(half4_t*)(As + (ar + s * 32) * 40 + ac) = h4;
            if (writeVh)
                *(half4_t*)(vhout + (tm + ar + s * 32) * 512 + kk + ac) = h4;
        }
        // ---- B-side: f16 staging (W1T / W2T)
        half8_t bb0 = *(const half8_t*)(Bg + (tn + srow) * 512 + kk + spart);
        half8_t bb1 = *(const half8_t*)(Bg + (tn + srow) * 512 + kk + spart + 8);
        *(half8_t*)(Bs + srow * 40 + spart) = bb0;
        *(half8_t*)(Bs + srow * 40 + spart + 8) = bb1;
        __syncthreads();
        half8_t af[4], bf[4];
#pragma unroll
        for (int i = 0; i < 4; ++i)
            af[i] = *(const half8_t*)(As + (wm + 16 * i + lr) * 40 + lk * 8);
#pragma unroll
        for (int j = 0; j < 4; ++j)
            bf[j] = *(const half8_t*)(Bs + (wn + 16 * j + lr) * 40 + lk * 8);
#pragma unroll
        for (int i = 0; i < 4; ++i)
#pragma unroll
            for (int j = 0; j < 4; ++j)
                acc[i][j] = __builtin_amdgcn_mfma_f32_16x16x32_f16(af[i], bf[j], acc[i][j], 0, 0, 0);
    }

    // C/D layout: col = lane&15, row = (lane>>4)*4 + reg
#pragma unroll
    for (int i = 0; i < 4; ++i) {
#pragma unroll
        for (int j = 0; j < 4; ++j) {
            const int gr0 = tm + wm + 16 * i + lk * 4;
            const int gc = tn + wn + 16 * j + lr;
            const float bv = bias[gc];
#pragma unroll
            for (int r = 0; r < 4; ++r) {
                const float e = __builtin_amdgcn_exp2f(KC * (acc[i][j][r] + bv));
                Cg[(gr0 + r) * NU + gc] = (_Float16)fminf(e, 60000.f);
            }
        }
    }
}

// ---------------- K3a: score + mask + softmax + attn-out. Grid 512 (b, qpair), 1024 thr.
// Wave-cooperative rows: wave (qh = w&1, vslice = w>>1) streams 32 Evp rows; 64 lanes
// load 16B each (coalesced 1KB row), each lane covers 8 u's, wred_sum folds the score.
__global__ __launch_bounds__(1024, 8) void score_kernel(
        const _Float16* __restrict__ Eqh, const _Float16* __restrict__ Evp,
        const _Float16* __restrict__ Vwh, const int* __restrict__ enc_mask,
        const float* __restrict__ CVbp, float* __restrict__ out) {
    const int bid = blockIdx.x;
    const int b = bid & 15, qp = bid >> 4;
    const int q0 = qp * 2;
    const int t = threadIdx.x;
    const int w = t >> 6, l = t & 63;
    const int qh = w & 1;
    const int vs = w >> 1;

    __shared__ float scL[2][256];
    __shared__ float rs[2][4], ss[2][4];

    const half8_t eq8 = *(const half8_t*)(Eqh + (b * NTQ + q0 + qh) * NU + l * 8);
    const half8_t vw8 = *(const half8_t*)(Vwh + l * 8);
    const half2_t e0 = {eq8[0], eq8[1]}, e1 = {eq8[2], eq8[3]},
                  e2 = {eq8[4], eq8[5]}, e3 = {eq8[6], eq8[7]};
    const half2_t w0 = {vw8[0], vw8[1]}, w1 = {vw8[2], vw8[3]},
                  w2 = {vw8[4], vw8[5]}, w3 = {vw8[6], vw8[7]};
    const half2_t one2 = {(_Float16)1.0f, (_Float16)1.0f};

    const _Float16* evb = Evp + (b * NTV + vs * 32) * NU + l * 8;
#pragma unroll 4
    for (int r = 0; r < 32; ++r) {
        const half8_t ev8 = *(const half8_t*)(evb + r * NU);
        const half2_t v0 = {ev8[0], ev8[1]}, v1 = {ev8[2], ev8[3]},
                      v2 = {ev8[4], ev8[5]}, v3 = {ev8[6], ev8[7]};
        const half2_t p0 = e0 * v0 + one2;
        const half2_t p1 = e1 * v1 + one2;
        const half2_t p2 = e2 * v2 + one2;
        const half2_t p3 = e3 * v3 + one2;
        const half2_t r0 = {RCPH(p0[0]), RCPH(p0[1])};
        const half2_t r1 = {RCPH(p1[0]), RCPH(p1[1])};
        const half2_t r2 = {RCPH(p2[0]), RCPH(p2[1])};
        const half2_t r3 = {RCPH(p3[0]), RCPH(p3[1])};
        float a0 = FDOT2(w0, r0, 0.f);
        a0 = FDOT2(w1, r1, a0);
        float a1 = FDOT2(w2, r2, 0.f);
        a1 = FDOT2(w3, r3, a1);
        float s = wred_sum(a0 + a1);
        if (l == 0) scL[qh][vs * 32 + r] = s;
    }
    __syncthreads();

    if (t < 512) {
        const int q = t >> 8, v = t & 255;
        const int ll = t & 63, w4 = (t >> 6) & 3;
        float sc = CVbp[0] - 2.f * scL[q][v];
        sc -= enc_mask[b * NTV + v] ? 0.f : 1e9f;
        float m = wred_max(sc);
        if (ll == 0) rs[q][w4] = m;
        __syncthreads();
        m = fmaxf(fmaxf(rs[q][0], rs[q][1]), fmaxf(rs[q][2], rs[q][3]));
        const float LOG2E = 1.4426950408889634f;
        const float ee = __builtin_amdgcn_exp2f((sc - m) * LOG2E);
        float t0 = wred_sum(ee);
        if (ll == 0) ss[q][w4] = t0;
        __syncthreads();
        const float S = (ss[q][0] + ss[q][1]) + (ss[q][2] + ss[q][3]);
        const float a = ee * __builtin_amdgcn_rcpf(S);
        float* out_attn = out + NB * NTQ * ND;
        out_attn[(b * NTQ + q0 + q) * NTV + v] = a;
    } else {
        __syncthreads();
        __syncthreads();
    }
}

// ---------------- K3b: context = attn @ values (f16 vh). Grid 256 (b, qquad), 1024 thr.
__global__ __launch_bounds__(1024) void ctx_kernel(
        const _Float16* __restrict__ vh, float* __restrict__ out) {
    const int bid = blockIdx.x;
    const int b = bid & 15, qq = bid >> 4;
    const int q0 = qq * 4;
    const int t = threadIdx.x;

    __shared__ float attL[4][256];
    __shared__ float ctxp[4][4][516];

    const float* attn_in = out + NB * NTQ * ND;
    attL[t >> 8][t & 255] = attn_in[(b * NTQ + q0 + (t >> 8)) * NTV + (t & 255)];
    __syncthreads();

    {
        const int vg = t >> 8;
        const int dp = t & 255;
        const _Float16* vsrc = vh + (b * NTV + vg * 64) * ND + dp * 2;
        float c0x = 0.f, c0y = 0.f, c1x = 0.f, c1y = 0.f;
        float c2x = 0.f, c2y = 0.f, c3x = 0.f, c3y = 0.f;
#pragma unroll 4
        for (int vi = 0; vi < 64; ++vi) {
            const half2_t vv = *(const half2_t*)(vsrc + vi * ND);
            const float vx = (float)vv[0], vy = (float)vv[1];
            const int v = vg * 64 + vi;
            const float aw0 = attL[0][v], aw1 = attL[1][v];
            const float aw2 = attL[2][v], aw3 = attL[3][v];
            c0x = fmaf(aw0, vx, c0x); c0y = fmaf(aw0, vy, c0y);
            c1x = fmaf(aw1, vx, c1x); c1y = fmaf(aw1, vy, c1y);
            c2x = fmaf(aw2, vx, c2x); c2y = fmaf(aw2, vy, c2y);
            c3x = fmaf(aw3, vx, c3x); c3y = fmaf(aw3, vy, c3y);
        }
        *(float2*)&ctxp[0][vg][dp * 2] = make_float2(c0x, c0y);
        *(float2*)&ctxp[1][vg][dp * 2] = make_float2(c1x, c1y);
        *(float2*)&ctxp[2][vg][dp * 2] = make_float2(c2x, c2y);
        *(float2*)&ctxp[3][vg][dp * 2] = make_float2(c3x, c3y);
    }
    __syncthreads();
#pragma unroll
    for (int k = 0; k < 2; ++k) {
        const int idx = t + k * 1024;
        const int cq = idx >> 9, d = idx & 511;
        float s = (ctxp[cq][0][d] + ctxp[cq][1][d]) + (ctxp[cq][2][d] + ctxp[cq][3][d]);
        out[(b * NTQ + q0 + cq) * ND + d] = s;
    }
}

extern "C" void kernel_launch(void* const* d_in, const int* in_sizes, int n_in,
                              void* d_out, int out_size, void* d_ws, size_t ws_size,
                              hipStream_t stream) {
    const float* query  = (const float*)d_in[0];
    const float* values = (const float*)d_in[1];
    const int*   emask  = (const int*)d_in[2];
    const float* W1     = (const float*)d_in[3];
    const float* b1     = (const float*)d_in[4];
    const float* W2     = (const float*)d_in[5];
    const float* b2     = (const float*)d_in[6];
    const float* Vw     = (const float*)d_in[7];
    const float* Vb     = (const float*)d_in[8];
    float* out = (float*)d_out;

    char* ws = (char*)d_ws;
    _Float16* W1T = (_Float16*)(ws + 0);          //  512 KB [U][D] f16
    _Float16* W2T = (_Float16*)(ws + 524288);     //  512 KB [U][D] f16
    _Float16* vh  = (_Float16*)(ws + 2097152);    //    4 MB [B*TV][D] f16
    _Float16* Eqh = (_Float16*)(ws + 6291456);    //    1 MB [B*TQ][U] f16 exp2
    _Float16* Evp = (_Float16*)(ws + 7340032);    //    4 MB [B][TV][U] f16 exp2 (v-major)
    _Float16* Vwh = (_Float16*)(ws + 11534336);   //    1 KB [U] f16
    float* CVb    = (float*)(ws + 11539456);      //    4 B

    prep_kernel<<<dim3(513), dim3(256), 0, stream>>>(W1, W2, Vw, Vb, W1T, W2T, Vwh, CVb);
    proj_gemm_kernel<<<dim3(160), dim3(256), 0, stream>>>(query, values, W1T, W2T,
                                                          b1, b2, Eqh, Evp, vh);
    score_kernel<<<dim3(512), dim3(1024), 0, stream>>>(Eqh, Evp, Vwh, emask, CVb, out);
    ctx_kernel<<<dim3(256), dim3(1024), 0, stream>>>(vh, out);
}

// Round 9
// 60.680 us; speedup vs baseline: 1.2572x; 1.2572x over previous
//
#include <hip/hip_runtime.h>

#define NB  16
#define NTQ 64
#define NTV 256
#define ND  512
#define NU  512

typedef _Float16 half8_t __attribute__((ext_vector_type(8)));
typedef _Float16 half4_t __attribute__((ext_vector_type(4)));
typedef _Float16 half2_t __attribute__((ext_vector_type(2)));
typedef float floatx4 __attribute__((ext_vector_type(4)));

#if __has_builtin(__builtin_amdgcn_fdot2)
#define FDOT2(a, b, c) __builtin_amdgcn_fdot2((a), (b), (c), false)
#else
#define FDOT2(a, b, c) ((c) + (float)((a)[0]) * (float)((b)[0]) + (float)((a)[1]) * (float)((b)[1]))
#endif
#if __has_builtin(__builtin_amdgcn_rcph)
#define RCPH(x) ((_Float16)__builtin_amdgcn_rcph((_Float16)(x)))
#else
#define RCPH(x) ((_Float16)__builtin_amdgcn_rcpf((float)(x)))
#endif

__device__ __forceinline__ float wred_sum(float x) {
#pragma unroll
    for (int m = 1; m < 64; m <<= 1) x += __shfl_xor(x, m, 64);
    return x;
}
__device__ __forceinline__ float wred_max(float x) {
#pragma unroll
    for (int m = 1; m < 64; m <<= 1) x = fmaxf(x, __shfl_xor(x, m, 64));
    return x;
}

// ---------------- K1: prep (transpose W1/W2 -> f16; Vwh; CVb)
__global__ __launch_bounds__(256) void prep_kernel(
        const float* __restrict__ W1, const float* __restrict__ W2,
        const float* __restrict__ Vw, const float* __restrict__ Vb,
        _Float16* __restrict__ W1T, _Float16* __restrict__ W2T,
        _Float16* __restrict__ Vwh, float* __restrict__ CVb) {
    const int blk = blockIdx.x;
    const int t = threadIdx.x;
    __shared__ float tb[32][33];
    if (blk < 512) {
        const float* W = (blk < 256) ? W1 : W2;
        _Float16* WT = (blk < 256) ? W1T : W2T;
        const int tile = blk & 255;
        const int tr = tile >> 4, tc = tile & 15;
        const int c = t & 31, r8 = t >> 5;
#pragma unroll
        for (int i = 0; i < 4; ++i) {
            int r = r8 + 8 * i;
            tb[r][c] = W[(tr * 32 + r) * 512 + tc * 32 + c];
        }
        __syncthreads();
#pragma unroll
        for (int i = 0; i < 4; ++i) {
            int r = r8 + 8 * i;
            WT[(tc * 32 + r) * 512 + tr * 32 + c] = (_Float16)tb[c][r];
        }
    } else {
        const float v0 = Vw[t], v1 = Vw[t + 256];
        Vwh[t] = (_Float16)v0;
        Vwh[t + 256] = (_Float16)v1;
        float s = wred_sum(v0 + v1);
        const int l = t & 63, w = t >> 6;
        __shared__ float ws4[4];
        if (l == 0) ws4[w] = s;
        __syncthreads();
        if (t == 0) CVb[0] = ws4[0] + ws4[1] + ws4[2] + ws4[3] + Vb[0];
    }
}

// ---------------- K2: projections as two plain GEMMs, f32 A loaded directly (fused cvt),
// reg-staged DOUBLE-BUFFERED pipeline (issue-early / write-late), 64x128 tiles, 320 blocks.
// bid < 64 : Eqh[m][u] = f16(min(exp2(KC*(query@W1 + b1)), 60000))   M=1024  (m=(b,q))
// bid >= 64: Evp[m][u] = f16(min(exp2(KC*(values@W2 + b2)), 60000))  M=4096  (m=(b,v), v-major)
__global__ __launch_bounds__(256, 2) void proj_gemm_kernel(
        const float* __restrict__ query, const float* __restrict__ values,
        const _Float16* __restrict__ W1T, const _Float16* __restrict__ W2T,
        const float* __restrict__ b1, const float* __restrict__ b2,
        _Float16* __restrict__ Eqh, _Float16* __restrict__ Evp) {
    __shared__ __align__(16) _Float16 As[2][64 * 40];
    __shared__ __align__(16) _Float16 Bs[2][128 * 40];
    const float KC = 2.8853900817779268f;  // 2*log2(e)
    const int bid = blockIdx.x;
    const int t = threadIdx.x;
    const int l = t & 63, w = t >> 6;

    const float* Agf; const _Float16* Bg; const float* bias; _Float16* Cg;
    int mt, nt;
    if (bid < 64) {
        mt = bid >> 2; nt = bid & 3;
        Agf = query; Bg = W1T; bias = b1; Cg = Eqh;
    } else {
        const int vb = bid - 64;
        mt = vb >> 2; nt = vb & 3;
        Agf = values; Bg = W2T; bias = b2; Cg = Evp;
    }
    const int tm = mt * 64, tn = nt * 128;

    // staging maps
    const int arow = t >> 2, acol = (t & 3) * 8;        // A: 64 rows x 32 k, 8 f32/thread
    const int brow = t >> 1, bcol = (t & 1) * 16;       // B: 128 rows x 32 k, 16 f16/thread
    const float* aptr = Agf + (tm + arow) * 512 + acol;
    const _Float16* bptr = Bg + (tn + brow) * 512 + bcol;

    // wave -> 32x64 subtile
    const int wm = (w & 1) * 32, wn = (w >> 1) * 64;
    const int lr = l & 15, lk = l >> 4;

    floatx4 acc[2][4] = {};
    float4 ar0, ar1; half8_t br0, br1;

#define LOADK(kk) do { \
        const float* ap = aptr + (kk) * 32; \
        ar0 = *(const float4*)ap; ar1 = *(const float4*)(ap + 4); \
        const _Float16* bp = bptr + (kk) * 32; \
        br0 = *(const half8_t*)bp; br1 = *(const half8_t*)(bp + 8); \
    } while (0)
#define STOREK(buf) do { \
        half8_t h = {(_Float16)ar0.x, (_Float16)ar0.y, (_Float16)ar0.z, (_Float16)ar0.w, \
                     (_Float16)ar1.x, (_Float16)ar1.y, (_Float16)ar1.z, (_Float16)ar1.w}; \
        *(half8_t*)(As[buf] + arow * 40 + acol) = h; \
        *(half8_t*)(Bs[buf] + brow * 40 + bcol) = br0; \
        *(half8_t*)(Bs[buf] + brow * 40 + bcol + 8) = br1; \
    } while (0)

    LOADK(0);
    STOREK(0);
    __syncthreads();

    for (int kk = 0; kk < 16; ++kk) {
        const int cur = kk & 1;
        if (kk < 15) LOADK(kk + 1);          // issue early: latency hides under compute
        half8_t af[2], bf[4];
#pragma unroll
        for (int i = 0; i < 2; ++i)
            af[i] = *(const half8_t*)(As[cur] + (wm + 16 * i + lr) * 40 + lk * 8);
#pragma unroll
        for (int j = 0; j < 4; ++j)
            bf[j] = *(const half8_t*)(Bs[cur] + (wn + 16 * j + lr) * 40 + lk * 8);
#pragma unroll
        for (int i = 0; i < 2; ++i)
#pragma unroll
            for (int j = 0; j < 4; ++j)
                acc[i][j] = __builtin_amdgcn_mfma_f32_16x16x32_f16(af[i], bf[j], acc[i][j], 0, 0, 0);
        if (kk < 15) STOREK(cur ^ 1);        // write late into the other buffer
        __syncthreads();                     // one barrier per K-step
    }

    // C/D layout: col = lane&15, row = (lane>>4)*4 + reg
#pragma unroll
    for (int i = 0; i < 2; ++i) {
#pragma unroll
        for (int j = 0; j < 4; ++j) {
            const int gr0 = tm + wm + 16 * i + lk * 4;
            const int gc = tn + wn + 16 * j + lr;
            const float bv = bias[gc];
#pragma unroll
            for (int r = 0; r < 4; ++r) {
                const float e = __builtin_amdgcn_exp2f(KC * (acc[i][j][r] + bv));
                Cg[(gr0 + r) * NU + gc] = (_Float16)fminf(e, 60000.f);
            }
        }
    }
#undef LOADK
#undef STOREK
}

// ---------------- K3a: score + mask + softmax + attn-out. Grid 512 (b, qpair), 1024 thr.
// Wave-cooperative rows: wave (qh = w&1, vslice = w>>1) streams 32 Evp rows; 64 lanes
// load 16B each (coalesced 1KB row), each lane covers 8 u's, wred_sum folds the score.
__global__ __launch_bounds__(1024, 8) void score_kernel(
        const _Float16* __restrict__ Eqh, const _Float16* __restrict__ Evp,
        const _Float16* __restrict__ Vwh, const int* __restrict__ enc_mask,
        const float* __restrict__ CVbp, float* __restrict__ out) {
    const int bid = blockIdx.x;
    const int b = bid & 15, qp = bid >> 4;
    const int q0 = qp * 2;
    const int t = threadIdx.x;
    const int w = t >> 6, l = t & 63;
    const int qh = w & 1;
    const int vs = w >> 1;

    __shared__ float scL[2][256];
    __shared__ float rs[2][4], ss[2][4];

    const half8_t eq8 = *(const half8_t*)(Eqh + (b * NTQ + q0 + qh) * NU + l * 8);
    const half8_t vw8 = *(const half8_t*)(Vwh + l * 8);
    const half2_t e0 = {eq8[0], eq8[1]}, e1 = {eq8[2], eq8[3]},
                  e2 = {eq8[4], eq8[5]}, e3 = {eq8[6], eq8[7]};
    const half2_t w0 = {vw8[0], vw8[1]}, w1 = {vw8[2], vw8[3]},
                  w2 = {vw8[4], vw8[5]}, w3 = {vw8[6], vw8[7]};
    const half2_t one2 = {(_Float16)1.0f, (_Float16)1.0f};

    const _Float16* evb = Evp + (b * NTV + vs * 32) * NU + l * 8;
#pragma unroll 4
    for (int r = 0; r < 32; ++r) {
        const half8_t ev8 = *(const half8_t*)(evb + r * NU);
        const half2_t v0 = {ev8[0], ev8[1]}, v1 = {ev8[2], ev8[3]},
                      v2 = {ev8[4], ev8[5]}, v3 = {ev8[6], ev8[7]};
        const half2_t p0 = e0 * v0 + one2;
        const half2_t p1 = e1 * v1 + one2;
        const half2_t p2 = e2 * v2 + one2;
        const half2_t p3 = e3 * v3 + one2;
        const half2_t r0 = {RCPH(p0[0]), RCPH(p0[1])};
        const half2_t r1 = {RCPH(p1[0]), RCPH(p1[1])};
        const half2_t r2 = {RCPH(p2[0]), RCPH(p2[1])};
        const half2_t r3 = {RCPH(p3[0]), RCPH(p3[1])};
        float a0 = FDOT2(w0, r0, 0.f);
        a0 = FDOT2(w1, r1, a0);
        float a1 = FDOT2(w2, r2, 0.f);
        a1 = FDOT2(w3, r3, a1);
        float s = wred_sum(a0 + a1);
        if (l == 0) scL[qh][vs * 32 + r] = s;
    }
    __syncthreads();

    if (t < 512) {
        const int q = t >> 8, v = t & 255;
        const int ll = t & 63, w4 = (t >> 6) & 3;
        float sc = CVbp[0] - 2.f * scL[q][v];
        sc -= enc_mask[b * NTV + v] ? 0.f : 1e9f;
        float m = wred_max(sc);
        if (ll == 0) rs[q][w4] = m;
        __syncthreads();
        m = fmaxf(fmaxf(rs[q][0], rs[q][1]), fmaxf(rs[q][2], rs[q][3]));
        const float LOG2E = 1.4426950408889634f;
        const float ee = __builtin_amdgcn_exp2f((sc - m) * LOG2E);
        float t0 = wred_sum(ee);
        if (ll == 0) ss[q][w4] = t0;
        __syncthreads();
        const float S = (ss[q][0] + ss[q][1]) + (ss[q][2] + ss[q][3]);
        const float a = ee * __builtin_amdgcn_rcpf(S);
        float* out_attn = out + NB * NTQ * ND;
        out_attn[(b * NTQ + q0 + q) * NTV + v] = a;
    } else {
        __syncthreads();
        __syncthreads();
    }
}

// ---------------- K3b: context = attn @ values (f32 direct). Grid 256 (b, qquad), 1024 thr.
__global__ __launch_bounds__(1024) void ctx_kernel(
        const float* __restrict__ values, float* __restrict__ out) {
    const int bid = blockIdx.x;
    const int b = bid & 15, qq = bid >> 4;
    const int q0 = qq * 4;
    const int t = threadIdx.x;

    __shared__ float attL[4][256];
    __shared__ float ctxp[4][4][516];

    const float* attn_in = out + NB * NTQ * ND;
    attL[t >> 8][t & 255] = attn_in[(b * NTQ + q0 + (t >> 8)) * NTV + (t & 255)];
    __syncthreads();

    {
        const int vg = t >> 8;           // 0..3 (64 v each)
        const int dp = t & 255;          // d = 2dp, 2dp+1
        const float* vsrc = values + (b * NTV + vg * 64) * ND + dp * 2;
        float c0x = 0.f, c0y = 0.f, c1x = 0.f, c1y = 0.f;
        float c2x = 0.f, c2y = 0.f, c3x = 0.f, c3y = 0.f;
#pragma unroll 4
        for (int vi = 0; vi < 64; ++vi) {
            const float2 vv = *(const float2*)(vsrc + vi * ND);
            const int v = vg * 64 + vi;
            const float aw0 = attL[0][v], aw1 = attL[1][v];
            const float aw2 = attL[2][v], aw3 = attL[3][v];
            c0x = fmaf(aw0, vv.x, c0x); c0y = fmaf(aw0, vv.y, c0y);
            c1x = fmaf(aw1, vv.x, c1x); c1y = fmaf(aw1, vv.y, c1y);
            c2x = fmaf(aw2, vv.x, c2x); c2y = fmaf(aw2, vv.y, c2y);
            c3x = fmaf(aw3, vv.x, c3x); c3y = fmaf(aw3, vv.y, c3y);
        }
        *(float2*)&ctxp[0][vg][dp * 2] = make_float2(c0x, c0y);
        *(float2*)&ctxp[1][vg][dp * 2] = make_float2(c1x, c1y);
        *(float2*)&ctxp[2][vg][dp * 2] = make_float2(c2x, c2y);
        *(float2*)&ctxp[3][vg][dp * 2] = make_float2(c3x, c3y);
    }
    __syncthreads();
#pragma unroll
    for (int k = 0; k < 2; ++k) {
        const int idx = t + k * 1024;
        const int cq = idx >> 9, d = idx & 511;
        float s = (ctxp[cq][0][d] + ctxp[cq][1][d]) + (ctxp[cq][2][d] + ctxp[cq][3][d]);
        out[(b * NTQ + q0 + cq) * ND + d] = s;
    }
}

extern "C" void kernel_launch(void* const* d_in, const int* in_sizes, int n_in,
                              void* d_out, int out_size, void* d_ws, size_t ws_size,
                              hipStream_t stream) {
    const float* query  = (const float*)d_in[0];
    const float* values = (const float*)d_in[1];
    const int*   emask  = (const int*)d_in[2];
    const float* W1     = (const float*)d_in[3];
    const float* b1     = (const float*)d_in[4];
    const float* W2     = (const float*)d_in[5];
    const float* b2     = (const float*)d_in[6];
    const float* Vw     = (const float*)d_in[7];
    const float* Vb     = (const float*)d_in[8];
    float* out = (float*)d_out;

    char* ws = (char*)d_ws;
    _Float16* W1T = (_Float16*)(ws + 0);          //  512 KB [U][D] f16
    _Float16* W2T = (_Float16*)(ws + 524288);     //  512 KB [U][D] f16
    _Float16* Eqh = (_Float16*)(ws + 6291456);    //    1 MB [B*TQ][U] f16 exp2
    _Float16* Evp = (_Float16*)(ws + 7340032);    //    4 MB [B][TV][U] f16 exp2 (v-major)
    _Float16* Vwh = (_Float16*)(ws + 11534336);   //    1 KB [U] f16
    float* CVb    = (float*)(ws + 11539456);      //    4 B

    prep_kernel<<<dim3(513), dim3(256), 0, stream>>>(W1, W2, Vw, Vb, W1T, W2T, Vwh, CVb);
    proj_gemm_kernel<<<dim3(320), dim3(256), 0, stream>>>(query, values, W1T, W2T,
                                                          b1, b2, Eqh, Evp);
    score_kernel<<<dim3(512), dim3(1024), 0, stream>>>(Eqh, Evp, Vwh, emask, CVb, out);
    ctx_kernel<<<dim3(256), dim3(1024), 0, stream>>>(values, out);
}

// Round 10
// 52.396 us; speedup vs baseline: 1.4560x; 1.1581x over previous
//
#include <hip/hip_runtime.h>

#define NB  16
#define NTQ 64
#define NTV 256
#define ND  512
#define NU  512

typedef _Float16 half8_t __attribute__((ext_vector_type(8)));
typedef _Float16 half4_t __attribute__((ext_vector_type(4)));
typedef _Float16 half2_t __attribute__((ext_vector_type(2)));
typedef float floatx4 __attribute__((ext_vector_type(4)));

#if __has_builtin(__builtin_amdgcn_fdot2)
#define FDOT2(a, b, c) __builtin_amdgcn_fdot2((a), (b), (c), false)
#else
#define FDOT2(a, b, c) ((c) + (float)((a)[0]) * (float)((b)[0]) + (float)((a)[1]) * (float)((b)[1]))
#endif
#if __has_builtin(__builtin_amdgcn_rcph)
#define RCPH(x) ((_Float16)__builtin_amdgcn_rcph((_Float16)(x)))
#else
#define RCPH(x) ((_Float16)__builtin_amdgcn_rcpf((float)(x)))
#endif

__device__ __forceinline__ float wred_sum(float x) {
#pragma unroll
    for (int m = 1; m < 64; m <<= 1) x += __shfl_xor(x, m, 64);
    return x;
}
__device__ __forceinline__ float wred_max(float x) {
#pragma unroll
    for (int m = 1; m < 64; m <<= 1) x = fmaxf(x, __shfl_xor(x, m, 64));
    return x;
}

// ---------------- K1: prep (transpose W1/W2 -> f16; Vwh; CVb)
__global__ __launch_bounds__(256) void prep_kernel(
        const float* __restrict__ W1, const float* __restrict__ W2,
        const float* __restrict__ Vw, const float* __restrict__ Vb,
        _Float16* __restrict__ W1T, _Float16* __restrict__ W2T,
        _Float16* __restrict__ Vwh, float* __restrict__ CVb) {
    const int blk = blockIdx.x;
    const int t = threadIdx.x;
    __shared__ float tb[32][33];
    if (blk < 512) {
        const float* W = (blk < 256) ? W1 : W2;
        _Float16* WT = (blk < 256) ? W1T : W2T;
        const int tile = blk & 255;
        const int tr = tile >> 4, tc = tile & 15;
        const int c = t & 31, r8 = t >> 5;
#pragma unroll
        for (int i = 0; i < 4; ++i) {
            int r = r8 + 8 * i;
            tb[r][c] = W[(tr * 32 + r) * 512 + tc * 32 + c];
        }
        __syncthreads();
#pragma unroll
        for (int i = 0; i < 4; ++i) {
            int r = r8 + 8 * i;
            WT[(tc * 32 + r) * 512 + tr * 32 + c] = (_Float16)tb[c][r];
        }
    } else {
        const float v0 = Vw[t], v1 = Vw[t + 256];
        Vwh[t] = (_Float16)v0;
        Vwh[t + 256] = (_Float16)v1;
        float s = wred_sum(v0 + v1);
        const int l = t & 63, w = t >> 6;
        __shared__ float ws4[4];
        if (l == 0) ws4[w] = s;
        __syncthreads();
        if (t == 0) CVb[0] = ws4[0] + ws4[1] + ws4[2] + ws4[3] + Vb[0];
    }
}

// ---------------- K2: projections, reg-staged double-buffered, 64x128 tiles, 320 blocks.
__global__ __launch_bounds__(256, 2) void proj_gemm_kernel(
        const float* __restrict__ query, const float* __restrict__ values,
        const _Float16* __restrict__ W1T, const _Float16* __restrict__ W2T,
        const float* __restrict__ b1, const float* __restrict__ b2,
        _Float16* __restrict__ Eqh, _Float16* __restrict__ Evp) {
    __shared__ __align__(16) _Float16 As[2][64 * 40];
    __shared__ __align__(16) _Float16 Bs[2][128 * 40];
    const float KC = 2.8853900817779268f;  // 2*log2(e)
    const int bid = blockIdx.x;
    const int t = threadIdx.x;
    const int l = t & 63, w = t >> 6;

    const float* Agf; const _Float16* Bg; const float* bias; _Float16* Cg;
    int mt, nt;
    if (bid < 64) {
        mt = bid >> 2; nt = bid & 3;
        Agf = query; Bg = W1T; bias = b1; Cg = Eqh;
    } else {
        const int vb = bid - 64;
        mt = vb >> 2; nt = vb & 3;
        Agf = values; Bg = W2T; bias = b2; Cg = Evp;
    }
    const int tm = mt * 64, tn = nt * 128;

    const int arow = t >> 2, acol = (t & 3) * 8;
    const int brow = t >> 1, bcol = (t & 1) * 16;
    const float* aptr = Agf + (tm + arow) * 512 + acol;
    const _Float16* bptr = Bg + (tn + brow) * 512 + bcol;

    const int wm = (w & 1) * 32, wn = (w >> 1) * 64;
    const int lr = l & 15, lk = l >> 4;

    floatx4 acc[2][4] = {};
    float4 ar0, ar1; half8_t br0, br1;

#define LOADK(kk) do { \
        const float* ap = aptr + (kk) * 32; \
        ar0 = *(const float4*)ap; ar1 = *(const float4*)(ap + 4); \
        const _Float16* bp = bptr + (kk) * 32; \
        br0 = *(const half8_t*)bp; br1 = *(const half8_t*)(bp + 8); \
    } while (0)
#define STOREK(buf) do { \
        half8_t h = {(_Float16)ar0.x, (_Float16)ar0.y, (_Float16)ar0.z, (_Float16)ar0.w, \
                     (_Float16)ar1.x, (_Float16)ar1.y, (_Float16)ar1.z, (_Float16)ar1.w}; \
        *(half8_t*)(As[buf] + arow * 40 + acol) = h; \
        *(half8_t*)(Bs[buf] + brow * 40 + bcol) = br0; \
        *(half8_t*)(Bs[buf] + brow * 40 + bcol + 8) = br1; \
    } while (0)

    LOADK(0);
    STOREK(0);
    __syncthreads();

    for (int kk = 0; kk < 16; ++kk) {
        const int cur = kk & 1;
        if (kk < 15) LOADK(kk + 1);
        half8_t af[2], bf[4];
#pragma unroll
        for (int i = 0; i < 2; ++i)
            af[i] = *(const half8_t*)(As[cur] + (wm + 16 * i + lr) * 40 + lk * 8);
#pragma unroll
        for (int j = 0; j < 4; ++j)
            bf[j] = *(const half8_t*)(Bs[cur] + (wn + 16 * j + lr) * 40 + lk * 8);
#pragma unroll
        for (int i = 0; i < 2; ++i)
#pragma unroll
            for (int j = 0; j < 4; ++j)
                acc[i][j] = __builtin_amdgcn_mfma_f32_16x16x32_f16(af[i], bf[j], acc[i][j], 0, 0, 0);
        if (kk < 15) STOREK(cur ^ 1);
        __syncthreads();
    }

    // C/D layout: col = lane&15, row = (lane>>4)*4 + reg
#pragma unroll
    for (int i = 0; i < 2; ++i) {
#pragma unroll
        for (int j = 0; j < 4; ++j) {
            const int gr0 = tm + wm + 16 * i + lk * 4;
            const int gc = tn + wn + 16 * j + lr;
            const float bv = bias[gc];
#pragma unroll
            for (int r = 0; r < 4; ++r) {
                const float e = __builtin_amdgcn_exp2f(KC * (acc[i][j][r] + bv));
                Cg[(gr0 + r) * NU + gc] = (_Float16)fminf(e, 60000.f);
            }
        }
    }
#undef LOADK
#undef STOREK
}

// ---------------- K3a: score + mask + softmax + attn-out. Grid 512 (b, qpair), 1024 thr.
// v3: (1) mask-skip whole rows (wave-uniform branch; skipped rows store 0 partials —
//     softmax's -1e9 penalty makes their weight 0 regardless);
//     (2) reduce only 64->8 lanes in the main loop (3 shfl, classes by l&7);
//     softmax phase sums the final 8 from scL8 (padded [9] -> conflict-free).
__global__ __launch_bounds__(1024, 8) void score_kernel(
        const _Float16* __restrict__ Eqh, const _Float16* __restrict__ Evp,
        const _Float16* __restrict__ Vwh, const int* __restrict__ enc_mask,
        const float* __restrict__ CVbp, float* __restrict__ out) {
    const int bid = blockIdx.x;
    const int b = bid & 15, qp = bid >> 4;
    const int q0 = qp * 2;
    const int t = threadIdx.x;
    const int w = t >> 6, l = t & 63;
    const int qh = w & 1;
    const int vs = w >> 1;

    __shared__ float scL8[2][256][9];   // 18 KB, pad 9 -> conflict-free scalar reads
    __shared__ float rs[2][4], ss[2][4];

    const half8_t eq8 = *(const half8_t*)(Eqh + (b * NTQ + q0 + qh) * NU + l * 8);
    const half8_t vw8 = *(const half8_t*)(Vwh + l * 8);
    const half2_t e0 = {eq8[0], eq8[1]}, e1 = {eq8[2], eq8[3]},
                  e2 = {eq8[4], eq8[5]}, e3 = {eq8[6], eq8[7]};
    const half2_t w0 = {vw8[0], vw8[1]}, w1 = {vw8[2], vw8[3]},
                  w2 = {vw8[4], vw8[5]}, w3 = {vw8[6], vw8[7]};
    const half2_t one2 = {(_Float16)1.0f, (_Float16)1.0f};

    // row-mask bits for this wave's 32 rows (wave-uniform in SGPR via ballot)
    int mv = 0;
    if (l < 32) mv = enc_mask[b * NTV + vs * 32 + l];
    const unsigned long long mbits = __ballot(mv != 0);

    const _Float16* evb = Evp + (b * NTV + vs * 32) * NU + l * 8;
#pragma unroll 4
    for (int r = 0; r < 32; ++r) {
        if ((mbits >> r) & 1ull) {
            const half8_t ev8 = *(const half8_t*)(evb + r * NU);
            const half2_t v0 = {ev8[0], ev8[1]}, v1 = {ev8[2], ev8[3]},
                          v2 = {ev8[4], ev8[5]}, v3 = {ev8[6], ev8[7]};
            const half2_t p0 = e0 * v0 + one2;
            const half2_t p1 = e1 * v1 + one2;
            const half2_t p2 = e2 * v2 + one2;
            const half2_t p3 = e3 * v3 + one2;
            const half2_t r0 = {RCPH(p0[0]), RCPH(p0[1])};
            const half2_t r1 = {RCPH(p1[0]), RCPH(p1[1])};
            const half2_t r2 = {RCPH(p2[0]), RCPH(p2[1])};
            const half2_t r3 = {RCPH(p3[0]), RCPH(p3[1])};
            float a0 = FDOT2(w0, r0, 0.f);
            a0 = FDOT2(w1, r1, a0);
            float a1 = FDOT2(w2, r2, 0.f);
            a1 = FDOT2(w3, r3, a1);
            float a = a0 + a1;
            a += __shfl_xor(a, 32, 64);   // reduce 64 -> 8 (3-deep chain)
            a += __shfl_xor(a, 16, 64);
            a += __shfl_xor(a, 8, 64);
            if (l < 8) scL8[qh][vs * 32 + r][l] = a;
        } else {
            if (l < 8) scL8[qh][vs * 32 + r][l] = 0.f;
        }
    }
    __syncthreads();

    if (t < 512) {
        const int q = t >> 8, v = t & 255;
        const int ll = t & 63, w4 = (t >> 6) & 3;
        float s = 0.f;
#pragma unroll
        for (int i = 0; i < 8; ++i) s += scL8[q][v][i];
        float sc = CVbp[0] - 2.f * s;
        sc -= enc_mask[b * NTV + v] ? 0.f : 1e9f;
        float m = wred_max(sc);
        if (ll == 0) rs[q][w4] = m;
        __syncthreads();
        m = fmaxf(fmaxf(rs[q][0], rs[q][1]), fmaxf(rs[q][2], rs[q][3]));
        const float LOG2E = 1.4426950408889634f;
        const float ee = __builtin_amdgcn_exp2f((sc - m) * LOG2E);
        float t0 = wred_sum(ee);
        if (ll == 0) ss[q][w4] = t0;
        __syncthreads();
        const float S = (ss[q][0] + ss[q][1]) + (ss[q][2] + ss[q][3]);
        const float a = ee * __builtin_amdgcn_rcpf(S);
        float* out_attn = out + NB * NTQ * ND;
        out_attn[(b * NTQ + q0 + q) * NTV + v] = a;
    } else {
        __syncthreads();
        __syncthreads();
    }
}

// ---------------- K3b: context = attn @ values (f32 direct). Grid 256 (b, qquad), 1024 thr.
__global__ __launch_bounds__(1024) void ctx_kernel(
        const float* __restrict__ values, float* __restrict__ out) {
    const int bid = blockIdx.x;
    const int b = bid & 15, qq = bid >> 4;
    const int q0 = qq * 4;
    const int t = threadIdx.x;

    __shared__ float attL[4][256];
    __shared__ float ctxp[4][4][516];

    const float* attn_in = out + NB * NTQ * ND;
    attL[t >> 8][t & 255] = attn_in[(b * NTQ + q0 + (t >> 8)) * NTV + (t & 255)];
    __syncthreads();

    {
        const int vg = t >> 8;
        const int dp = t & 255;
        const float* vsrc = values + (b * NTV + vg * 64) * ND + dp * 2;
        float c0x = 0.f, c0y = 0.f, c1x = 0.f, c1y = 0.f;
        float c2x = 0.f, c2y = 0.f, c3x = 0.f, c3y = 0.f;
#pragma unroll 4
        for (int vi = 0; vi < 64; ++vi) {
            const float2 vv = *(const float2*)(vsrc + vi * ND);
            const int v = vg * 64 + vi;
            const float aw0 = attL[0][v], aw1 = attL[1][v];
            const float aw2 = attL[2][v], aw3 = attL[3][v];
            c0x = fmaf(aw0, vv.x, c0x); c0y = fmaf(aw0, vv.y, c0y);
            c1x = fmaf(aw1, vv.x, c1x); c1y = fmaf(aw1, vv.y, c1y);
            c2x = fmaf(aw2, vv.x, c2x); c2y = fmaf(aw2, vv.y, c2y);
            c3x = fmaf(aw3, vv.x, c3x); c3y = fmaf(aw3, vv.y, c3y);
        }
        *(float2*)&ctxp[0][vg][dp * 2] = make_float2(c0x, c0y);
        *(float2*)&ctxp[1][vg][dp * 2] = make_float2(c1x, c1y);
        *(float2*)&ctxp[2][vg][dp * 2] = make_float2(c2x, c2y);
        *(float2*)&ctxp[3][vg][dp * 2] = make_float2(c3x, c3y);
    }
    __syncthreads();
#pragma unroll
    for (int k = 0; k < 2; ++k) {
        const int idx = t + k * 1024;
        const int cq = idx >> 9, d = idx & 511;
        float s = (ctxp[cq][0][d] + ctxp[cq][1][d]) + (ctxp[cq][2][d] + ctxp[cq][3][d]);
        out[(b * NTQ + q0 + cq) * ND + d] = s;
    }
}

extern "C" void kernel_launch(void* const* d_in, const int* in_sizes, int n_in,
                              void* d_out, int out_size, void* d_ws, size_t ws_size,
                              hipStream_t stream) {
    const float* query  = (const float*)d_in[0];
    const float* values = (const float*)d_in[1];
    const int*   emask  = (const int*)d_in[2];
    const float* W1     = (const float*)d_in[3];
    const float* b1     = (const float*)d_in[4];
    const float* W2     = (const float*)d_in[5];
    const float* b2     = (const float*)d_in[6];
    const float* Vw     = (const float*)d_in[7];
    const float* Vb     = (const float*)d_in[8];
    float* out = (float*)d_out;

    char* ws = (char*)d_ws;
    _Float16* W1T = (_Float16*)(ws + 0);          //  512 KB [U][D] f16
    _Float16* W2T = (_Float16*)(ws + 524288);     //  512 KB [U][D] f16
    _Float16* Eqh = (_Float16*)(ws + 6291456);    //    1 MB [B*TQ][U] f16 exp2
    _Float16* Evp = (_Float16*)(ws + 7340032);    //    4 MB [B][TV][U] f16 exp2 (v-major)
    _Float16* Vwh = (_Float16*)(ws + 11534336);   //    1 KB [U] f16
    float* CVb    = (float*)(ws + 11539456);      //    4 B

    prep_kernel<<<dim3(513), dim3(256), 0, stream>>>(W1, W2, Vw, Vb, W1T, W2T, Vwh, CVb);
    proj_gemm_kernel<<<dim3(320), dim3(256), 0, stream>>>(query, values, W1T, W2T,
                                                          b1, b2, Eqh, Evp);
    score_kernel<<<dim3(512), dim3(1024), 0, stream>>>(Eqh, Evp, Vwh, emask, CVb, out);
    ctx_kernel<<<dim3(256), dim3(1024), 0, stream>>>(values, out);
}